// Round 11
// baseline (691.226 us; speedup 1.0000x reference)
//
#include <hip/hip_runtime.h>
#include <float.h>

#define NB      65536
#define IN_DIM  512
#define HID     256
#define LAT     64
#define NLAYERS 3
#define NK      2048
#define DELTA   1e-2f

typedef __attribute__((ext_vector_type(8)))  short s16x8;   // 8 bf16 (4 VGPR)
typedef __attribute__((ext_vector_type(16))) float fp32x16; // MFMA 32x32 acc

__device__ __forceinline__ unsigned short f2bf(float v) {  // fp32 -> bf16 RNE
  unsigned u = __float_as_uint(v);
  unsigned r = (u + 0x7fffu + ((u >> 16) & 1u)) >> 16;
  return (unsigned short)r;
}
__device__ __forceinline__ float bf2f(unsigned short h) {
  return __uint_as_float((unsigned)h << 16);
}

// ---------------------------------------------------------------------------
// enc2-style GEMM (N=64): BM=128, BN=64, BK=32, TM=8, TN=4. (bit-exact np)
// ---------------------------------------------------------------------------
template<bool RELU>
__global__ __launch_bounds__(256) void gemm_f32(
    const float* __restrict__ A, const float* __restrict__ W,
    const float* __restrict__ bias, float* __restrict__ C,
    int M, int N, int K) {
  __shared__ float As[32][132];
  __shared__ float Bs[32][64];
  const int tid = threadIdx.x;
  const int cg  = tid & 15;
  const int rg  = tid >> 4;
  const int m0  = blockIdx.x * 128;
  const int n0  = blockIdx.y * 64;

  float acc[8][4];
#pragma unroll
  for (int i = 0; i < 8; ++i)
#pragma unroll
    for (int j = 0; j < 4; ++j) acc[i][j] = 0.f;

  for (int k0 = 0; k0 < K; k0 += 32) {
#pragma unroll
    for (int p = 0; p < 4; ++p) {
      int a = tid + p * 256;
      int row = a >> 3, kq = (a & 7) * 4;
      float4 v = *reinterpret_cast<const float4*>(&A[(size_t)(m0 + row) * K + k0 + kq]);
      As[kq + 0][row] = v.x; As[kq + 1][row] = v.y;
      As[kq + 2][row] = v.z; As[kq + 3][row] = v.w;
    }
#pragma unroll
    for (int p = 0; p < 2; ++p) {
      int a = tid + p * 256;
      int kk = a >> 4, nq = (a & 15) * 4;
      *reinterpret_cast<float4*>(&Bs[kk][nq]) =
          *reinterpret_cast<const float4*>(&W[(size_t)(k0 + kk) * N + n0 + nq]);
    }
    __syncthreads();
#pragma unroll
    for (int kk = 0; kk < 32; ++kk) {
      float4 a0 = *reinterpret_cast<const float4*>(&As[kk][rg * 8]);
      float4 a1 = *reinterpret_cast<const float4*>(&As[kk][rg * 8 + 4]);
      float4 b0 = *reinterpret_cast<const float4*>(&Bs[kk][cg * 4]);
      float av[8] = {a0.x, a0.y, a0.z, a0.w, a1.x, a1.y, a1.z, a1.w};
      float bv[4] = {b0.x, b0.y, b0.z, b0.w};
#pragma unroll
      for (int i = 0; i < 8; ++i)
#pragma unroll
        for (int j = 0; j < 4; ++j)
          acc[i][j] = fmaf(av[i], bv[j], acc[i][j]);
    }
    __syncthreads();
  }

  float4 bb = *reinterpret_cast<const float4*>(&bias[n0 + cg * 4]);
  float bv[4] = {bb.x, bb.y, bb.z, bb.w};
#pragma unroll
  for (int i = 0; i < 8; ++i) {
    float vals[4];
#pragma unroll
    for (int j = 0; j < 4; ++j) {
      float v = __fadd_rn(acc[i][j], bv[j]);
      if (RELU) v = fmaxf(v, 0.f);
      vals[j] = v;
    }
    float4 o; o.x = vals[0]; o.y = vals[1]; o.z = vals[2]; o.w = vals[3];
    *reinterpret_cast<float4*>(&C[(size_t)(m0 + rg * 8 + i) * N + n0 + cg * 4]) = o;
  }
}

// ---------------------------------------------------------------------------
// Big fp32 GEMM: BM=128, BN=128, BK=16, TM=8, TN=8. (bit-exact np; encoder)
// ---------------------------------------------------------------------------
template<bool RELU>
__global__ __launch_bounds__(256) void gemm128(
    const float* __restrict__ A, const float* __restrict__ W,
    const float* __restrict__ bias, float* __restrict__ C,
    int M, int N, int K) {
  __shared__ float As[16][132];
  __shared__ float Bs[16][132];
  const int tid  = threadIdx.x;
  const int cg   = tid & 15;
  const int rg   = tid >> 4;
  const int sw   = (cg >> 2) & 1;
  const int colA = cg * 8 + sw * 4;
  const int colB = cg * 8 + (sw ^ 1) * 4;
  const int m0   = blockIdx.x * 128;
  const int n0   = blockIdx.y * 128;

  const int arow = tid >> 2;
  const int akq  = (tid & 3) * 4;
  const int bk   = tid >> 5;
  const int bn   = (tid & 31) * 4;

  const float* Ap0 = A + (size_t)(m0 + arow) * K + akq;
  const float* Ap1 = A + (size_t)(m0 + arow + 64) * K + akq;
  const float* Wp0 = W + (size_t)bk * N + n0 + bn;
  const float* Wp1 = W + (size_t)(bk + 8) * N + n0 + bn;

  float acc[8][8];
#pragma unroll
  for (int i = 0; i < 8; ++i)
#pragma unroll
    for (int j = 0; j < 8; ++j) acc[i][j] = 0.f;

  float4 av0, av1, bv0, bv1;
  av0 = *reinterpret_cast<const float4*>(Ap0);
  av1 = *reinterpret_cast<const float4*>(Ap1);
  bv0 = *reinterpret_cast<const float4*>(Wp0);
  bv1 = *reinterpret_cast<const float4*>(Wp1);

  auto write_tile = [&]() {
    As[akq + 0][arow] = av0.x; As[akq + 1][arow] = av0.y;
    As[akq + 2][arow] = av0.z; As[akq + 3][arow] = av0.w;
    As[akq + 0][arow + 64] = av1.x; As[akq + 1][arow + 64] = av1.y;
    As[akq + 2][arow + 64] = av1.z; As[akq + 3][arow + 64] = av1.w;
    *reinterpret_cast<float4*>(&Bs[bk][bn])     = bv0;
    *reinterpret_cast<float4*>(&Bs[bk + 8][bn]) = bv1;
  };
  auto compute_tile = [&]() {
#pragma unroll
    for (int kk = 0; kk < 16; ++kk) {
      float4 a0 = *reinterpret_cast<const float4*>(&As[kk][rg * 8]);
      float4 a1 = *reinterpret_cast<const float4*>(&As[kk][rg * 8 + 4]);
      float4 b0 = *reinterpret_cast<const float4*>(&Bs[kk][colA]);
      float4 b1 = *reinterpret_cast<const float4*>(&Bs[kk][colB]);
      float rv[8] = {a0.x, a0.y, a0.z, a0.w, a1.x, a1.y, a1.z, a1.w};
      float cv[8] = {b0.x, b0.y, b0.z, b0.w, b1.x, b1.y, b1.z, b1.w};
#pragma unroll
      for (int i = 0; i < 8; ++i)
#pragma unroll
        for (int j = 0; j < 8; ++j)
          acc[i][j] = fmaf(rv[i], cv[j], acc[i][j]);
    }
  };

  write_tile();
  __syncthreads();
#pragma unroll 1
  for (int k0 = 16; k0 < K; k0 += 16) {
    av0 = *reinterpret_cast<const float4*>(Ap0 + k0);
    av1 = *reinterpret_cast<const float4*>(Ap1 + k0);
    bv0 = *reinterpret_cast<const float4*>(Wp0 + (size_t)k0 * N);
    bv1 = *reinterpret_cast<const float4*>(Wp1 + (size_t)k0 * N);
    compute_tile();
    __syncthreads();
    write_tile();
    __syncthreads();
  }
  compute_tile();

  float4 bA = *reinterpret_cast<const float4*>(&bias[n0 + colA]);
  float4 bB = *reinterpret_cast<const float4*>(&bias[n0 + colB]);
  float ba[8] = {bA.x, bA.y, bA.z, bA.w, bB.x, bB.y, bB.z, bB.w};
#pragma unroll
  for (int i = 0; i < 8; ++i) {
    size_t row = (size_t)(m0 + rg * 8 + i);
    float o[8];
#pragma unroll
    for (int j = 0; j < 8; ++j) {
      float v = __fadd_rn(acc[i][j], ba[j]);
      if (RELU) v = fmaxf(v, 0.f);
      o[j] = v;
    }
    float4 oA; oA.x = o[0]; oA.y = o[1]; oA.z = o[2]; oA.w = o[3];
    float4 oB; oB.x = o[4]; oB.y = o[5]; oB.z = o[6]; oB.w = o[7];
    *reinterpret_cast<float4*>(&C[row * N + n0 + colA]) = oA;
    *reinterpret_cast<float4*>(&C[row * N + n0 + colB]) = oB;
  }
}

// ---------------------------------------------------------------------------
// cnorm[l][k] = sum_d C[l][k][d]^2, numpy pairwise 8-acc order.
// ---------------------------------------------------------------------------
__global__ void cnorm_f32(const float* __restrict__ cb, float* __restrict__ cn) {
  int i = blockIdx.x * blockDim.x + threadIdx.x;
  if (i >= NLAYERS * NK) return;
  const float* row = cb + (size_t)i * LAT;
  float r[8];
#pragma unroll
  for (int j = 0; j < 8; ++j) r[j] = 0.f;
#pragma unroll
  for (int t = 0; t < 8; ++t)
#pragma unroll
    for (int j = 0; j < 8; ++j) {
      float v = row[t * 8 + j];
      r[j] = __fadd_rn(r[j], __fmul_rn(v, v));
    }
  cn[i] = __fadd_rn(__fadd_rn(__fadd_rn(r[0], r[1]), __fadd_rn(r[2], r[3])),
                    __fadd_rn(__fadd_rn(r[4], r[5]), __fadd_rn(r[6], r[7])));
}

// ---------------------------------------------------------------------------
// Codebook bf16 hi/lo splits, MFMA-frag-linear (r3 verbatim, NO -2 fold).
// ---------------------------------------------------------------------------
__global__ void split_cb(const float* __restrict__ cb,
                         unsigned short* __restrict__ cbf) {
  const int sid  = blockIdx.x * 256 + threadIdx.x;   // 0 .. 49151
  const int lane = sid & 63;
  const int grp  = sid >> 6;
  const int fg   = grp & 7;
  const int chl  = grp >> 3;
  const int nt = fg >> 2, ks = fg & 3;
  const int layer = chl >> 5, ch = chl & 31;
  const int code = ch * 64 + nt * 32 + (lane & 31);
  const int k0 = ks * 16 + (lane >> 5) * 8;
  const float* src = cb + ((size_t)layer * NK + code) * LAT + k0;
  float4 a = *(const float4*)src;
  float4 b = *(const float4*)(src + 4);
  float v[8] = {a.x, a.y, a.z, a.w, b.x, b.y, b.z, b.w};
  s16x8 hi, lo;
#pragma unroll
  for (int i = 0; i < 8; ++i) {
    unsigned short h = f2bf(v[i]);
    hi[i] = (short)h;
    lo[i] = (short)f2bf(__fsub_rn(v[i], bf2f(h)));
  }
  *(s16x8*)(cbf + ((size_t)grp * 2 + 0) * 512 + lane * 8) = hi;
  *(s16x8*)(cbf + ((size_t)grp * 2 + 1) * 512 + lane * 8) = lo;
}

// ---------------------------------------------------------------------------
// Weight bf16 hi/lo splits, frag-linear (decoder).
// ---------------------------------------------------------------------------
__global__ void split_w(const float* __restrict__ W,
                        unsigned short* __restrict__ wf, int K, int N) {
  const int total = (K / 16) * (N / 32) * 64;
  const int idx = blockIdx.x * 256 + threadIdx.x;
  if (idx >= total) return;
  const int lane = idx & 63;
  const int grp  = idx >> 6;
  const int ntn  = N / 32;
  const int ks   = grp / ntn;
  const int ntg  = grp % ntn;
  const int col  = ntg * 32 + (lane & 31);
  const int k0   = ks * 16 + (lane >> 5) * 8;
  s16x8 hi, lo;
#pragma unroll
  for (int i = 0; i < 8; ++i) {
    float v = W[(size_t)(k0 + i) * N + col];
    unsigned short h = f2bf(v);
    hi[i] = (short)h;
    lo[i] = (short)f2bf(__fsub_rn(v, bf2f(h)));
  }
  *(s16x8*)(wf + ((size_t)grp * 2 + 0) * 512 + lane * 8) = hi;
  *(s16x8*)(wf + ((size_t)grp * 2 + 1) * 512 + lane * 8) = lo;
}

// ---------------------------------------------------------------------------
// Residual quantization: ROUND-3 KERNEL + T5 s_setprio around MFMA cluster
// (P2 has no barriers -> waves role-diverse -> setprio applicable per m191).
// Everything else byte-identical to the measured-330us kernel. Codes exact.
// ---------------------------------------------------------------------------
__global__ __launch_bounds__(256, 2) void rq_mfma(
    const float* __restrict__ zg,            // [B][64] == out_res layer 0 (z)
    const float* __restrict__ cb,            // [3][2048][64] fp32
    const unsigned short* __restrict__ cbf,  // frag-linear bf16 splits
    const float* __restrict__ cnorm,         // [3][2048]
    float* __restrict__ out_codes,           // [3][B] as float
    float* __restrict__ out_quant,           // [B][64]
    float* __restrict__ out_res) {           // [3][B][64]
  __shared__ float m1S[128][2];
  __shared__ int   candS[128][8];
  __shared__ int   cntS[128][2];
  __shared__ int   flagS[128][2];
  __shared__ int   selS[128];
  __shared__ float rnS[128];
  __shared__ float bestD[256];
  __shared__ int   bestK[256];

  const int tid   = threadIdx.x;
  const int w     = tid >> 6;
  const int rgrp  = w >> 1;       // rows rgrp*64 ..
  const int chalf = w & 1;        // chunks chalf*16 ..
  const int lane  = tid & 63;
  const int half  = lane >> 5;
  const int lcol  = lane & 31;
  const int rb0   = blockIdx.x * 128;

  s16x8 ah[2][4], al[2][4];       // residual splits, [Msub][kstep]

  for (int layer = 0; layer < NLAYERS; ++layer) {
    const float* cbL = cb + (size_t)layer * NK * LAT;
    const float* cnL = cnorm + (size_t)layer * NK;
    const unsigned short* cbfL = cbf + (size_t)layer * (NK * LAT * 2);
    float* resL = out_res + (size_t)layer * NB * LAT;

    // ---- P0: residual = z - q (np order); chalf==0 waves write resL ----
#pragma unroll
    for (int m = 0; m < 2; ++m) {
      const size_t row = (size_t)(rb0 + rgrp * 64 + m * 32 + lcol);
#pragma unroll
      for (int ks = 0; ks < 4; ++ks) {
        const int k0 = ks * 16 + half * 8;
        const float* zp = zg + row * LAT + k0;
        float4 a = *(const float4*)zp;
        float4 b = *(const float4*)(zp + 4);
        float r[8] = {a.x, a.y, a.z, a.w, b.x, b.y, b.z, b.w};
        if (layer > 0) {
          const float* qp = out_quant + row * LAT + k0;
          float4 qa = *(const float4*)qp;
          float4 qb = *(const float4*)(qp + 4);
          float q[8] = {qa.x, qa.y, qa.z, qa.w, qb.x, qb.y, qb.z, qb.w};
#pragma unroll
          for (int i = 0; i < 8; ++i) r[i] = __fsub_rn(r[i], q[i]);
          if (chalf == 0) {
            float4 o0 = {r[0], r[1], r[2], r[3]};
            float4 o1 = {r[4], r[5], r[6], r[7]};
            *(float4*)(resL + row * LAT + k0) = o0;
            *(float4*)(resL + row * LAT + k0 + 4) = o1;
          }
        }
#pragma unroll
        for (int i = 0; i < 8; ++i) {
          unsigned short hh = f2bf(r[i]);
          float hf = bf2f(hh);
          ah[m][ks][i] = (short)hh;
          al[m][ks][i] = (short)f2bf(__fsub_rn(r[i], hf));
        }
      }
    }
    __syncthreads();   // resL visible for rnorm / rescue

    // ---- P1: row norms (numpy pairwise 8-acc) ----
    if (tid < 128) {
      const float* rp = resL + (size_t)(rb0 + tid) * LAT;
      float r8[8] = {0.f, 0.f, 0.f, 0.f, 0.f, 0.f, 0.f, 0.f};
#pragma unroll
      for (int tb = 0; tb < 8; ++tb) {
        float4 x0 = *(const float4*)(rp + tb * 8);
        float4 x1 = *(const float4*)(rp + tb * 8 + 4);
        float v[8] = {x0.x, x0.y, x0.z, x0.w, x1.x, x1.y, x1.z, x1.w};
#pragma unroll
        for (int j = 0; j < 8; ++j)
          r8[j] = __fadd_rn(r8[j], __fmul_rn(v[j], v[j]));
      }
      rnS[tid] = __fadd_rn(
          __fadd_rn(__fadd_rn(r8[0], r8[1]), __fadd_rn(r8[2], r8[3])),
          __fadd_rn(__fadd_rn(r8[4], r8[5]), __fadd_rn(r8[6], r8[7])));
    }
    __syncthreads();

    // ---- P2: approximate distances via MFMA, per-lane best-2 tracking ----
    float v1[2][16], v2[2][16];
    int   i1[2][16];
#pragma unroll
    for (int m = 0; m < 2; ++m)
#pragma unroll
      for (int r = 0; r < 16; ++r) {
        v1[m][r] = FLT_MAX; v2[m][r] = FLT_MAX; i1[m][r] = 0;
      }

#pragma unroll 1
    for (int ch = 0; ch < 16; ++ch) {
      const int chg = chalf * 16 + ch;
      const unsigned short* cf = cbfL + (size_t)chg * 8192;
#pragma unroll
      for (int nt = 0; nt < 2; ++nt) {
        const int kbase = chg * 64 + nt * 32 + lcol;
        float cnv = cnL[kbase];
        s16x8 bh[4], bl[4];
#pragma unroll
        for (int ks = 0; ks < 4; ++ks) {
          bh[ks] = *(const s16x8*)(cf + ((size_t)((nt * 4 + ks) * 2 + 0) * 64 + lane) * 8);
          bl[ks] = *(const s16x8*)(cf + ((size_t)((nt * 4 + ks) * 2 + 1) * 64 + lane) * 8);
        }
        fp32x16 acc0, acc1;
#pragma unroll
        for (int r = 0; r < 16; ++r) { acc0[r] = 0.f; acc1[r] = 0.f; }
        __builtin_amdgcn_s_setprio(1);   // T5: favor MFMA cluster
#pragma unroll
        for (int ks = 0; ks < 4; ++ks) {
          acc0 = __builtin_amdgcn_mfma_f32_32x32x16_bf16(ah[0][ks], bh[ks], acc0, 0, 0, 0);
          acc1 = __builtin_amdgcn_mfma_f32_32x32x16_bf16(ah[1][ks], bh[ks], acc1, 0, 0, 0);
          acc0 = __builtin_amdgcn_mfma_f32_32x32x16_bf16(ah[0][ks], bl[ks], acc0, 0, 0, 0);
          acc1 = __builtin_amdgcn_mfma_f32_32x32x16_bf16(ah[1][ks], bl[ks], acc1, 0, 0, 0);
          acc0 = __builtin_amdgcn_mfma_f32_32x32x16_bf16(al[0][ks], bh[ks], acc0, 0, 0, 0);
          acc1 = __builtin_amdgcn_mfma_f32_32x32x16_bf16(al[1][ks], bh[ks], acc1, 0, 0, 0);
        }
        __builtin_amdgcn_s_setprio(0);
#pragma unroll
        for (int r = 0; r < 16; ++r) {
          float d0 = fmaf(-2.f, acc0[r], cnv);
          bool c0 = d0 < v1[0][r];
          v2[0][r] = c0 ? v1[0][r] : fminf(v2[0][r], d0);
          v1[0][r] = c0 ? d0 : v1[0][r];
          i1[0][r] = c0 ? kbase : i1[0][r];
          float d1 = fmaf(-2.f, acc1[r], cnv);
          bool c1 = d1 < v1[1][r];
          v2[1][r] = c1 ? v1[1][r] : fminf(v2[1][r], d1);
          v1[1][r] = c1 ? d1 : v1[1][r];
          i1[1][r] = c1 ? kbase : i1[1][r];
        }
      }
    }

    // ---- P3: per-row min across lanes + both chalf waves; candidates ----
#pragma unroll
    for (int m = 0; m < 2; ++m)
#pragma unroll
      for (int r = 0; r < 16; ++r) {
        float m1 = v1[m][r];
        m1 = fminf(m1, __shfl_xor(m1, 1));
        m1 = fminf(m1, __shfl_xor(m1, 2));
        m1 = fminf(m1, __shfl_xor(m1, 4));
        m1 = fminf(m1, __shfl_xor(m1, 8));
        m1 = fminf(m1, __shfl_xor(m1, 16));
        const int rowloc = rgrp * 64 + m * 32 + (r & 3) + 8 * (r >> 2) + 4 * half;
        if (lcol == 0) m1S[rowloc][chalf] = m1;
      }
    __syncthreads();
#pragma unroll
    for (int m = 0; m < 2; ++m)
#pragma unroll
      for (int r = 0; r < 16; ++r) {
        const int rowloc = rgrp * 64 + m * 32 + (r & 3) + 8 * (r >> 2) + 4 * half;
        float thr = fminf(m1S[rowloc][0], m1S[rowloc][1]) + DELTA;
        unsigned long long bc = __ballot(v1[m][r] <= thr);
        unsigned long long bf = __ballot(v2[m][r] <= thr);
        unsigned mc = (unsigned)(bc >> (half * 32));
        unsigned mf = (unsigned)(bf >> (half * 32));
        int pos = __popc(mc & ((1u << lcol) - 1u));
        if (v1[m][r] <= thr && pos < 4) candS[rowloc][chalf * 4 + pos] = i1[m][r];
        if (lcol == 0) {
          int c = __popc(mc);
          cntS[rowloc][chalf]  = (c < 4) ? c : 4;
          flagS[rowloc][chalf] = (mf != 0u) || (c > 4);
        }
      }
    __syncthreads();

    // ---- Phase A: exact np recompute for candidates (unflagged rows) ----
    if (tid < 128) {
      const int t = tid;
      if ((flagS[t][0] | flagS[t][1]) == 0) {
        const float* rp = resL + (size_t)(rb0 + t) * LAT;
        float rr[64];
#pragma unroll
        for (int j = 0; j < 16; ++j) {
          float4 x = *(const float4*)(rp + j * 4);
          rr[j * 4 + 0] = x.x; rr[j * 4 + 1] = x.y;
          rr[j * 4 + 2] = x.z; rr[j * 4 + 3] = x.w;
        }
        const float rn = rnS[t];
        float bd = FLT_MAX; int bk = 0x7fffffff;
        const int c0 = cntS[t][0], c1n = cntS[t][1];
        for (int c = 0; c < c0 + c1n; ++c) {
          int k = candS[t][(c < c0) ? c : (4 + c - c0)];
          const float* cp = cbL + (size_t)k * LAT;
          float dot = 0.f;
#pragma unroll
          for (int j = 0; j < 64; ++j) dot = fmaf(rr[j], cp[j], dot);
          float d = __fadd_rn(__fsub_rn(rn, __fmul_rn(2.f, dot)), cnL[k]);
          if (d < bd || (d == bd && k < bk)) { bd = d; bk = k; }
        }
        selS[t] = bk;
        out_codes[(size_t)layer * NB + rb0 + t] = (float)bk;
      }
    }
    __syncthreads();

    // ---- Phase B: flagged rows -> full exact scan (rare) ----
#pragma unroll 1
    for (int t2 = 0; t2 < 128; ++t2) {
      if ((flagS[t2][0] | flagS[t2][1]) == 0) continue;
      const float* rp = resL + (size_t)(rb0 + t2) * LAT;
      const float rn = rnS[t2];
      float bd = FLT_MAX; int bk = 0x7fffffff;
#pragma unroll 1
      for (int j = 0; j < 8; ++j) {
        int k = tid * 8 + j;
        const float* cp = cbL + (size_t)k * LAT;
        float dot = 0.f;
        for (int q = 0; q < 64; ++q) dot = fmaf(rp[q], cp[q], dot);
        float d = __fadd_rn(__fsub_rn(rn, __fmul_rn(2.f, dot)), cnL[k]);
        if (d < bd || (d == bd && k < bk)) { bd = d; bk = k; }
      }
      bestD[tid] = bd; bestK[tid] = bk;
      __syncthreads();
      if (tid == 0) {
        float gd = FLT_MAX; int gk = 0x7fffffff;
        for (int i = 0; i < 256; ++i) {
          float d = bestD[i]; int k = bestK[i];
          if (d < gd || (d == gd && k < gk)) { gd = d; gk = k; }
        }
        selS[t2] = gk;
        out_codes[(size_t)layer * NB + rb0 + t2] = (float)gk;
      }
      __syncthreads();
    }

    // ---- Phase Q: quantized = C[code] + quantized (np order) ----
    if (chalf == 0) {
#pragma unroll
      for (int m = 0; m < 2; ++m) {
        const int rowloc = rgrp * 64 + m * 32 + lcol;
        const size_t row = (size_t)(rb0 + rowloc);
        const int sel = selS[rowloc];
        const float* cp = cbL + (size_t)sel * LAT;
#pragma unroll
        for (int ks = 0; ks < 4; ++ks) {
          const int k0 = ks * 16 + half * 8;
          float4 c0 = *(const float4*)(cp + k0);
          float4 c1 = *(const float4*)(cp + k0 + 4);
          float* qp = out_quant + row * LAT + k0;
          if (layer == 0) {
            *(float4*)qp = c0; *(float4*)(qp + 4) = c1;
          } else {
            float4 q0 = *(const float4*)qp;
            float4 q1 = *(const float4*)(qp + 4);
            q0.x = __fadd_rn(c0.x, q0.x); q0.y = __fadd_rn(c0.y, q0.y);
            q0.z = __fadd_rn(c0.z, q0.z); q0.w = __fadd_rn(c0.w, q0.w);
            q1.x = __fadd_rn(c1.x, q1.x); q1.y = __fadd_rn(c1.y, q1.y);
            q1.z = __fadd_rn(c1.z, q1.z); q1.w = __fadd_rn(c1.w, q1.w);
            *(float4*)qp = q0; *(float4*)(qp + 4) = q1;
          }
        }
      }
    }
    __syncthreads();
  }
}

// ---------------------------------------------------------------------------
// dec1: h = relu(q @ dw1 + b1), split-bf16 MFMA, output hi/lo bf16 planes.
// ---------------------------------------------------------------------------
__global__ __launch_bounds__(256) void dec1_mfma(
    const float* __restrict__ q, const unsigned short* __restrict__ wf,
    const float* __restrict__ bias,
    unsigned short* __restrict__ h_hi, unsigned short* __restrict__ h_lo) {
  const int tid  = threadIdx.x;
  const int w    = tid >> 6;
  const int lane = tid & 63;
  const int half = lane >> 5;
  const int lcol = lane & 31;
  const int m0   = blockIdx.x * 128 + w * 32;
  const int n0   = blockIdx.y * 128;

  fp32x16 acc[4];
#pragma unroll
  for (int nt = 0; nt < 4; ++nt)
#pragma unroll
    for (int r = 0; r < 16; ++r) acc[nt][r] = 0.f;

  const size_t arow = (size_t)(m0 + lcol);
#pragma unroll
  for (int ks = 0; ks < 4; ++ks) {
    const float* ap = q + arow * LAT + ks * 16 + half * 8;
    float4 a0 = *(const float4*)ap;
    float4 a1 = *(const float4*)(ap + 4);
    float av[8] = {a0.x, a0.y, a0.z, a0.w, a1.x, a1.y, a1.z, a1.w};
    s16x8 ah, al;
#pragma unroll
    for (int i = 0; i < 8; ++i) {
      unsigned short hh = f2bf(av[i]);
      ah[i] = (short)hh;
      al[i] = (short)f2bf(__fsub_rn(av[i], bf2f(hh)));
    }
    __builtin_amdgcn_s_setprio(1);
#pragma unroll
    for (int nt = 0; nt < 4; ++nt) {
      const int grp = ks * 8 + (blockIdx.y * 4 + nt);   // N/32 = 8
      const unsigned short* base = wf + (size_t)grp * 1024;
      s16x8 bh = *(const s16x8*)(base + lane * 8);
      s16x8 bl = *(const s16x8*)(base + 512 + lane * 8);
      acc[nt] = __builtin_amdgcn_mfma_f32_32x32x16_bf16(ah, bh, acc[nt], 0, 0, 0);
      acc[nt] = __builtin_amdgcn_mfma_f32_32x32x16_bf16(ah, bl, acc[nt], 0, 0, 0);
      acc[nt] = __builtin_amdgcn_mfma_f32_32x32x16_bf16(al, bh, acc[nt], 0, 0, 0);
    }
    __builtin_amdgcn_s_setprio(0);
  }

#pragma unroll
  for (int nt = 0; nt < 4; ++nt) {
    const int col = n0 + nt * 32 + lcol;
    const float b = bias[col];
#pragma unroll
    for (int r = 0; r < 16; ++r) {
      const int rowo = (r & 3) + 8 * (r >> 2) + 4 * half;
      const size_t grow = (size_t)(m0 + rowo);
      float v = fmaxf(__fadd_rn(acc[nt][r], b), 0.f);
      unsigned short hh = f2bf(v);
      h_hi[grow * HID + col] = hh;
      h_lo[grow * HID + col] = f2bf(__fsub_rn(v, bf2f(hh)));
    }
  }
}

// ---------------------------------------------------------------------------
// dec2: x_recon = h @ dw2 + b2 (split-bf16 MFMA, h from hi/lo planes).
// ---------------------------------------------------------------------------
__global__ __launch_bounds__(256) void dec2_mfma(
    const unsigned short* __restrict__ h_hi,
    const unsigned short* __restrict__ h_lo,
    const unsigned short* __restrict__ wf,
    const float* __restrict__ bias, float* __restrict__ C) {
  const int tid  = threadIdx.x;
  const int w    = tid >> 6;
  const int lane = tid & 63;
  const int half = lane >> 5;
  const int lcol = lane & 31;
  const int m0   = blockIdx.x * 128 + w * 32;
  const int n0   = blockIdx.y * 128;

  fp32x16 acc[4];
#pragma unroll
  for (int nt = 0; nt < 4; ++nt)
#pragma unroll
    for (int r = 0; r < 16; ++r) acc[nt][r] = 0.f;

  const size_t arow = (size_t)(m0 + lcol);
#pragma unroll 1
  for (int ks = 0; ks < 16; ++ks) {
    const size_t aoff = arow * HID + ks * 16 + half * 8;
    s16x8 ah = *(const s16x8*)(h_hi + aoff);
    s16x8 al = *(const s16x8*)(h_lo + aoff);
    __builtin_amdgcn_s_setprio(1);
#pragma unroll
    for (int nt = 0; nt < 4; ++nt) {
      const int grp = ks * 16 + (blockIdx.y * 4 + nt);  // N/32 = 16
      const unsigned short* base = wf + (size_t)grp * 1024;
      s16x8 bh = *(const s16x8*)(base + lane * 8);
      s16x8 bl = *(const s16x8*)(base + 512 + lane * 8);
      acc[nt] = __builtin_amdgcn_mfma_f32_32x32x16_bf16(ah, bh, acc[nt], 0, 0, 0);
      acc[nt] = __builtin_amdgcn_mfma_f32_32x32x16_bf16(ah, bl, acc[nt], 0, 0, 0);
      acc[nt] = __builtin_amdgcn_mfma_f32_32x32x16_bf16(al, bh, acc[nt], 0, 0, 0);
    }
    __builtin_amdgcn_s_setprio(0);
  }

#pragma unroll
  for (int nt = 0; nt < 4; ++nt) {
    const int col = n0 + nt * 32 + lcol;
    const float b = bias[col];
#pragma unroll
    for (int r = 0; r < 16; ++r) {
      const int rowo = (r & 3) + 8 * (r >> 2) + 4 * half;
      C[(size_t)(m0 + rowo) * IN_DIM + col] = __fadd_rn(acc[nt][r], b);
    }
  }
}

// ---------------------------------------------------------------------------
extern "C" void kernel_launch(void* const* d_in, const int* in_sizes, int n_in,
                              void* d_out, int out_size, void* d_ws, size_t ws_size,
                              hipStream_t stream) {
  (void)in_sizes; (void)n_in; (void)out_size;
  const float* x   = (const float*)d_in[0];
  const float* ew1 = (const float*)d_in[1];
  const float* eb1 = (const float*)d_in[2];
  const float* ew2 = (const float*)d_in[3];
  const float* eb2 = (const float*)d_in[4];
  const float* cbk = (const float*)d_in[5];
  const float* dw1 = (const float*)d_in[6];
  const float* db1 = (const float*)d_in[7];
  const float* dw2 = (const float*)d_in[8];
  const float* db2 = (const float*)d_in[9];

  float* out     = (float*)d_out;
  float* o_codes = out;                                   // 3*B
  float* o_xrec  = out + (size_t)NLAYERS * NB;            // B*512
  float* o_quant = o_xrec + (size_t)NB * IN_DIM;          // B*64
  float* o_res   = o_quant + (size_t)NB * LAT;            // 3*B*64

  char* ws = (char*)d_ws;
  float* h            = (float*)ws;                                  // 64 MB
  unsigned short* hhi = (unsigned short*)ws;                         // 32 MB
  unsigned short* hlo = (unsigned short*)(ws + (size_t)32 * 1024 * 1024);
  float* cn           = (float*)(ws + (size_t)64 * 1024 * 1024);     // 24 KB
  unsigned short* w1f = (unsigned short*)(ws + (size_t)64 * 1024 * 1024 + 32768);
  unsigned short* w2f = (unsigned short*)(ws + (size_t)64 * 1024 * 1024 + 32768 + 65536);
  const size_t ws_need = (size_t)64 * 1024 * 1024 + 32768 + 65536 + 524288;
  const bool fast_dec = ws_size >= ws_need;

  // codebook frag splits in the dead-until-dec2 tail of o_xrec (rq-only read)
  unsigned short* cbf = (unsigned short*)(o_xrec + (size_t)16 * 1024 * 1024);

  cnorm_f32<<<(NLAYERS * NK + 255) / 256, 256, 0, stream>>>(cbk, cn);
  split_cb<<<192, 256, 0, stream>>>(cbk, cbf);
  if (fast_dec) {
    split_w<<<((LAT / 16) * (HID / 32) * 64 + 255) / 256, 256, 0, stream>>>(dw1, w1f, LAT, HID);
    split_w<<<((HID / 16) * (IN_DIM / 32) * 64 + 255) / 256, 256, 0, stream>>>(dw2, w2f, HID, IN_DIM);
  }
  // encoder (bit-exact fp32; z -> codes chain must be exact)
  gemm128<true ><<<dim3(NB / 128, HID / 128), 256, 0, stream>>>(x, ew1, eb1, h,     NB, HID, IN_DIM);
  gemm_f32<false><<<dim3(NB / 128, LAT / 64),  256, 0, stream>>>(h, ew2, eb2, o_res, NB, LAT, HID);
  // residual quantization (r3 kernel + T5 setprio; codes exact)
  rq_mfma<<<NB / 128, 256, 0, stream>>>(o_res, cbk, cbf, cn, o_codes, o_quant, o_res);
  // decoder (split-bf16 MFMA + T5 setprio)
  if (fast_dec) {
    dec1_mfma<<<dim3(NB / 128, 2), 256, 0, stream>>>(o_quant, w1f, db1, hhi, hlo);
    dec2_mfma<<<dim3(NB / 128, 4), 256, 0, stream>>>(hhi, hlo, w2f, db2, o_xrec);
  } else {
    gemm128<true ><<<dim3(NB / 128, HID / 128),    256, 0, stream>>>(o_quant, dw1, db1, h,      NB, HID,    LAT);
    gemm128<false><<<dim3(NB / 128, IN_DIM / 128), 256, 0, stream>>>(h,       dw2, db2, o_xrec, NB, IN_DIM, HID);
  }
}

// Round 12
// 673.525 us; speedup vs baseline: 1.0263x; 1.0263x over previous
//
#include <hip/hip_runtime.h>
#include <float.h>

#define NB      65536
#define IN_DIM  512
#define HID     256
#define LAT     64
#define NLAYERS 3
#define NK      2048
#define DELTA   1e-2f

typedef __attribute__((ext_vector_type(8)))  short s16x8;   // 8 bf16 (4 VGPR)
typedef __attribute__((ext_vector_type(16))) float fp32x16; // MFMA 32x32 acc

__device__ __forceinline__ unsigned short f2bf(float v) {  // fp32 -> bf16 RNE
  unsigned u = __float_as_uint(v);
  unsigned r = (u + 0x7fffu + ((u >> 16) & 1u)) >> 16;
  return (unsigned short)r;
}
__device__ __forceinline__ float bf2f(unsigned short h) {
  return __uint_as_float((unsigned)h << 16);
}

// ---------------------------------------------------------------------------
// enc2-style GEMM (N=64): BM=128, BN=64, BK=32, TM=8, TN=4. (bit-exact np)
// ---------------------------------------------------------------------------
template<bool RELU>
__global__ __launch_bounds__(256) void gemm_f32(
    const float* __restrict__ A, const float* __restrict__ W,
    const float* __restrict__ bias, float* __restrict__ C,
    int M, int N, int K) {
  __shared__ float As[32][132];
  __shared__ float Bs[32][64];
  const int tid = threadIdx.x;
  const int cg  = tid & 15;
  const int rg  = tid >> 4;
  const int m0  = blockIdx.x * 128;
  const int n0  = blockIdx.y * 64;

  float acc[8][4];
#pragma unroll
  for (int i = 0; i < 8; ++i)
#pragma unroll
    for (int j = 0; j < 4; ++j) acc[i][j] = 0.f;

  for (int k0 = 0; k0 < K; k0 += 32) {
#pragma unroll
    for (int p = 0; p < 4; ++p) {
      int a = tid + p * 256;
      int row = a >> 3, kq = (a & 7) * 4;
      float4 v = *reinterpret_cast<const float4*>(&A[(size_t)(m0 + row) * K + k0 + kq]);
      As[kq + 0][row] = v.x; As[kq + 1][row] = v.y;
      As[kq + 2][row] = v.z; As[kq + 3][row] = v.w;
    }
#pragma unroll
    for (int p = 0; p < 2; ++p) {
      int a = tid + p * 256;
      int kk = a >> 4, nq = (a & 15) * 4;
      *reinterpret_cast<float4*>(&Bs[kk][nq]) =
          *reinterpret_cast<const float4*>(&W[(size_t)(k0 + kk) * N + n0 + nq]);
    }
    __syncthreads();
#pragma unroll
    for (int kk = 0; kk < 32; ++kk) {
      float4 a0 = *reinterpret_cast<const float4*>(&As[kk][rg * 8]);
      float4 a1 = *reinterpret_cast<const float4*>(&As[kk][rg * 8 + 4]);
      float4 b0 = *reinterpret_cast<const float4*>(&Bs[kk][cg * 4]);
      float av[8] = {a0.x, a0.y, a0.z, a0.w, a1.x, a1.y, a1.z, a1.w};
      float bv[4] = {b0.x, b0.y, b0.z, b0.w};
#pragma unroll
      for (int i = 0; i < 8; ++i)
#pragma unroll
        for (int j = 0; j < 4; ++j)
          acc[i][j] = fmaf(av[i], bv[j], acc[i][j]);
    }
    __syncthreads();
  }

  float4 bb = *reinterpret_cast<const float4*>(&bias[n0 + cg * 4]);
  float bv[4] = {bb.x, bb.y, bb.z, bb.w};
#pragma unroll
  for (int i = 0; i < 8; ++i) {
    float vals[4];
#pragma unroll
    for (int j = 0; j < 4; ++j) {
      float v = __fadd_rn(acc[i][j], bv[j]);
      if (RELU) v = fmaxf(v, 0.f);
      vals[j] = v;
    }
    float4 o; o.x = vals[0]; o.y = vals[1]; o.z = vals[2]; o.w = vals[3];
    *reinterpret_cast<float4*>(&C[(size_t)(m0 + rg * 8 + i) * N + n0 + cg * 4]) = o;
  }
}

// ---------------------------------------------------------------------------
// Big fp32 GEMM: BM=128, BN=128, BK=16, TM=8, TN=8. (bit-exact np; encoder)
// ---------------------------------------------------------------------------
template<bool RELU>
__global__ __launch_bounds__(256) void gemm128(
    const float* __restrict__ A, const float* __restrict__ W,
    const float* __restrict__ bias, float* __restrict__ C,
    int M, int N, int K) {
  __shared__ float As[16][132];
  __shared__ float Bs[16][132];
  const int tid  = threadIdx.x;
  const int cg   = tid & 15;
  const int rg   = tid >> 4;
  const int sw   = (cg >> 2) & 1;
  const int colA = cg * 8 + sw * 4;
  const int colB = cg * 8 + (sw ^ 1) * 4;
  const int m0   = blockIdx.x * 128;
  const int n0   = blockIdx.y * 128;

  const int arow = tid >> 2;
  const int akq  = (tid & 3) * 4;
  const int bk   = tid >> 5;
  const int bn   = (tid & 31) * 4;

  const float* Ap0 = A + (size_t)(m0 + arow) * K + akq;
  const float* Ap1 = A + (size_t)(m0 + arow + 64) * K + akq;
  const float* Wp0 = W + (size_t)bk * N + n0 + bn;
  const float* Wp1 = W + (size_t)(bk + 8) * N + n0 + bn;

  float acc[8][8];
#pragma unroll
  for (int i = 0; i < 8; ++i)
#pragma unroll
    for (int j = 0; j < 8; ++j) acc[i][j] = 0.f;

  float4 av0, av1, bv0, bv1;
  av0 = *reinterpret_cast<const float4*>(Ap0);
  av1 = *reinterpret_cast<const float4*>(Ap1);
  bv0 = *reinterpret_cast<const float4*>(Wp0);
  bv1 = *reinterpret_cast<const float4*>(Wp1);

  auto write_tile = [&]() {
    As[akq + 0][arow] = av0.x; As[akq + 1][arow] = av0.y;
    As[akq + 2][arow] = av0.z; As[akq + 3][arow] = av0.w;
    As[akq + 0][arow + 64] = av1.x; As[akq + 1][arow + 64] = av1.y;
    As[akq + 2][arow + 64] = av1.z; As[akq + 3][arow + 64] = av1.w;
    *reinterpret_cast<float4*>(&Bs[bk][bn])     = bv0;
    *reinterpret_cast<float4*>(&Bs[bk + 8][bn]) = bv1;
  };
  auto compute_tile = [&]() {
#pragma unroll
    for (int kk = 0; kk < 16; ++kk) {
      float4 a0 = *reinterpret_cast<const float4*>(&As[kk][rg * 8]);
      float4 a1 = *reinterpret_cast<const float4*>(&As[kk][rg * 8 + 4]);
      float4 b0 = *reinterpret_cast<const float4*>(&Bs[kk][colA]);
      float4 b1 = *reinterpret_cast<const float4*>(&Bs[kk][colB]);
      float rv[8] = {a0.x, a0.y, a0.z, a0.w, a1.x, a1.y, a1.z, a1.w};
      float cv[8] = {b0.x, b0.y, b0.z, b0.w, b1.x, b1.y, b1.z, b1.w};
#pragma unroll
      for (int i = 0; i < 8; ++i)
#pragma unroll
        for (int j = 0; j < 8; ++j)
          acc[i][j] = fmaf(rv[i], cv[j], acc[i][j]);
    }
  };

  write_tile();
  __syncthreads();
#pragma unroll 1
  for (int k0 = 16; k0 < K; k0 += 16) {
    av0 = *reinterpret_cast<const float4*>(Ap0 + k0);
    av1 = *reinterpret_cast<const float4*>(Ap1 + k0);
    bv0 = *reinterpret_cast<const float4*>(Wp0 + (size_t)k0 * N);
    bv1 = *reinterpret_cast<const float4*>(Wp1 + (size_t)k0 * N);
    compute_tile();
    __syncthreads();
    write_tile();
    __syncthreads();
  }
  compute_tile();

  float4 bA = *reinterpret_cast<const float4*>(&bias[n0 + colA]);
  float4 bB = *reinterpret_cast<const float4*>(&bias[n0 + colB]);
  float ba[8] = {bA.x, bA.y, bA.z, bA.w, bB.x, bB.y, bB.z, bB.w};
#pragma unroll
  for (int i = 0; i < 8; ++i) {
    size_t row = (size_t)(m0 + rg * 8 + i);
    float o[8];
#pragma unroll
    for (int j = 0; j < 8; ++j) {
      float v = __fadd_rn(acc[i][j], ba[j]);
      if (RELU) v = fmaxf(v, 0.f);
      o[j] = v;
    }
    float4 oA; oA.x = o[0]; oA.y = o[1]; oA.z = o[2]; oA.w = o[3];
    float4 oB; oB.x = o[4]; oB.y = o[5]; oB.z = o[6]; oB.w = o[7];
    *reinterpret_cast<float4*>(&C[row * N + n0 + colA]) = oA;
    *reinterpret_cast<float4*>(&C[row * N + n0 + colB]) = oB;
  }
}

// ---------------------------------------------------------------------------
// cnorm[l][k] = sum_d C[l][k][d]^2, numpy pairwise 8-acc order.
// ---------------------------------------------------------------------------
__global__ void cnorm_f32(const float* __restrict__ cb, float* __restrict__ cn) {
  int i = blockIdx.x * blockDim.x + threadIdx.x;
  if (i >= NLAYERS * NK) return;
  const float* row = cb + (size_t)i * LAT;
  float r[8];
#pragma unroll
  for (int j = 0; j < 8; ++j) r[j] = 0.f;
#pragma unroll
  for (int t = 0; t < 8; ++t)
#pragma unroll
    for (int j = 0; j < 8; ++j) {
      float v = row[t * 8 + j];
      r[j] = __fadd_rn(r[j], __fmul_rn(v, v));
    }
  cn[i] = __fadd_rn(__fadd_rn(__fadd_rn(r[0], r[1]), __fadd_rn(r[2], r[3])),
                    __fadd_rn(__fadd_rn(r[4], r[5]), __fadd_rn(r[6], r[7])));
}

// ---------------------------------------------------------------------------
// Codebook bf16 hi/lo splits, MFMA-frag-linear (r3 verbatim, NO -2 fold).
// ---------------------------------------------------------------------------
__global__ void split_cb(const float* __restrict__ cb,
                         unsigned short* __restrict__ cbf) {
  const int sid  = blockIdx.x * 256 + threadIdx.x;   // 0 .. 49151
  const int lane = sid & 63;
  const int grp  = sid >> 6;
  const int fg   = grp & 7;
  const int chl  = grp >> 3;
  const int nt = fg >> 2, ks = fg & 3;
  const int layer = chl >> 5, ch = chl & 31;
  const int code = ch * 64 + nt * 32 + (lane & 31);
  const int k0 = ks * 16 + (lane >> 5) * 8;
  const float* src = cb + ((size_t)layer * NK + code) * LAT + k0;
  float4 a = *(const float4*)src;
  float4 b = *(const float4*)(src + 4);
  float v[8] = {a.x, a.y, a.z, a.w, b.x, b.y, b.z, b.w};
  s16x8 hi, lo;
#pragma unroll
  for (int i = 0; i < 8; ++i) {
    unsigned short h = f2bf(v[i]);
    hi[i] = (short)h;
    lo[i] = (short)f2bf(__fsub_rn(v[i], bf2f(h)));
  }
  *(s16x8*)(cbf + ((size_t)grp * 2 + 0) * 512 + lane * 8) = hi;
  *(s16x8*)(cbf + ((size_t)grp * 2 + 1) * 512 + lane * 8) = lo;
}

// ---------------------------------------------------------------------------
// Weight bf16 hi/lo splits, frag-linear (decoder).
// ---------------------------------------------------------------------------
__global__ void split_w(const float* __restrict__ W,
                        unsigned short* __restrict__ wf, int K, int N) {
  const int total = (K / 16) * (N / 32) * 64;
  const int idx = blockIdx.x * 256 + threadIdx.x;
  if (idx >= total) return;
  const int lane = idx & 63;
  const int grp  = idx >> 6;
  const int ntn  = N / 32;
  const int ks   = grp / ntn;
  const int ntg  = grp % ntn;
  const int col  = ntg * 32 + (lane & 31);
  const int k0   = ks * 16 + (lane >> 5) * 8;
  s16x8 hi, lo;
#pragma unroll
  for (int i = 0; i < 8; ++i) {
    float v = W[(size_t)(k0 + i) * N + col];
    unsigned short h = f2bf(v);
    hi[i] = (short)h;
    lo[i] = (short)f2bf(__fsub_rn(v, bf2f(h)));
  }
  *(s16x8*)(wf + ((size_t)grp * 2 + 0) * 512 + lane * 8) = hi;
  *(s16x8*)(wf + ((size_t)grp * 2 + 1) * 512 + lane * 8) = lo;
}

// ---------------------------------------------------------------------------
// Residual quantization: r3 kernel + T5 setprio in P2 only (A/B-validated:
// 330 -> 323-325 us). Codes provably exact via Delta-window numpy rescue.
// ---------------------------------------------------------------------------
__global__ __launch_bounds__(256, 2) void rq_mfma(
    const float* __restrict__ zg,            // [B][64] == out_res layer 0 (z)
    const float* __restrict__ cb,            // [3][2048][64] fp32
    const unsigned short* __restrict__ cbf,  // frag-linear bf16 splits
    const float* __restrict__ cnorm,         // [3][2048]
    float* __restrict__ out_codes,           // [3][B] as float
    float* __restrict__ out_quant,           // [B][64]
    float* __restrict__ out_res) {           // [3][B][64]
  __shared__ float m1S[128][2];
  __shared__ int   candS[128][8];
  __shared__ int   cntS[128][2];
  __shared__ int   flagS[128][2];
  __shared__ int   selS[128];
  __shared__ float rnS[128];
  __shared__ float bestD[256];
  __shared__ int   bestK[256];

  const int tid   = threadIdx.x;
  const int w     = tid >> 6;
  const int rgrp  = w >> 1;       // rows rgrp*64 ..
  const int chalf = w & 1;        // chunks chalf*16 ..
  const int lane  = tid & 63;
  const int half  = lane >> 5;
  const int lcol  = lane & 31;
  const int rb0   = blockIdx.x * 128;

  s16x8 ah[2][4], al[2][4];       // residual splits, [Msub][kstep]

  for (int layer = 0; layer < NLAYERS; ++layer) {
    const float* cbL = cb + (size_t)layer * NK * LAT;
    const float* cnL = cnorm + (size_t)layer * NK;
    const unsigned short* cbfL = cbf + (size_t)layer * (NK * LAT * 2);
    float* resL = out_res + (size_t)layer * NB * LAT;

    // ---- P0: residual = z - q (np order); chalf==0 waves write resL ----
#pragma unroll
    for (int m = 0; m < 2; ++m) {
      const size_t row = (size_t)(rb0 + rgrp * 64 + m * 32 + lcol);
#pragma unroll
      for (int ks = 0; ks < 4; ++ks) {
        const int k0 = ks * 16 + half * 8;
        const float* zp = zg + row * LAT + k0;
        float4 a = *(const float4*)zp;
        float4 b = *(const float4*)(zp + 4);
        float r[8] = {a.x, a.y, a.z, a.w, b.x, b.y, b.z, b.w};
        if (layer > 0) {
          const float* qp = out_quant + row * LAT + k0;
          float4 qa = *(const float4*)qp;
          float4 qb = *(const float4*)(qp + 4);
          float q[8] = {qa.x, qa.y, qa.z, qa.w, qb.x, qb.y, qb.z, qb.w};
#pragma unroll
          for (int i = 0; i < 8; ++i) r[i] = __fsub_rn(r[i], q[i]);
          if (chalf == 0) {
            float4 o0 = {r[0], r[1], r[2], r[3]};
            float4 o1 = {r[4], r[5], r[6], r[7]};
            *(float4*)(resL + row * LAT + k0) = o0;
            *(float4*)(resL + row * LAT + k0 + 4) = o1;
          }
        }
#pragma unroll
        for (int i = 0; i < 8; ++i) {
          unsigned short hh = f2bf(r[i]);
          float hf = bf2f(hh);
          ah[m][ks][i] = (short)hh;
          al[m][ks][i] = (short)f2bf(__fsub_rn(r[i], hf));
        }
      }
    }
    __syncthreads();   // resL visible for rnorm / rescue

    // ---- P1: row norms (numpy pairwise 8-acc) ----
    if (tid < 128) {
      const float* rp = resL + (size_t)(rb0 + tid) * LAT;
      float r8[8] = {0.f, 0.f, 0.f, 0.f, 0.f, 0.f, 0.f, 0.f};
#pragma unroll
      for (int tb = 0; tb < 8; ++tb) {
        float4 x0 = *(const float4*)(rp + tb * 8);
        float4 x1 = *(const float4*)(rp + tb * 8 + 4);
        float v[8] = {x0.x, x0.y, x0.z, x0.w, x1.x, x1.y, x1.z, x1.w};
#pragma unroll
        for (int j = 0; j < 8; ++j)
          r8[j] = __fadd_rn(r8[j], __fmul_rn(v[j], v[j]));
      }
      rnS[tid] = __fadd_rn(
          __fadd_rn(__fadd_rn(r8[0], r8[1]), __fadd_rn(r8[2], r8[3])),
          __fadd_rn(__fadd_rn(r8[4], r8[5]), __fadd_rn(r8[6], r8[7])));
    }
    __syncthreads();

    // ---- P2: approximate distances via MFMA, per-lane best-2 tracking ----
    float v1[2][16], v2[2][16];
    int   i1[2][16];
#pragma unroll
    for (int m = 0; m < 2; ++m)
#pragma unroll
      for (int r = 0; r < 16; ++r) {
        v1[m][r] = FLT_MAX; v2[m][r] = FLT_MAX; i1[m][r] = 0;
      }

#pragma unroll 1
    for (int ch = 0; ch < 16; ++ch) {
      const int chg = chalf * 16 + ch;
      const unsigned short* cf = cbfL + (size_t)chg * 8192;
#pragma unroll
      for (int nt = 0; nt < 2; ++nt) {
        const int kbase = chg * 64 + nt * 32 + lcol;
        float cnv = cnL[kbase];
        s16x8 bh[4], bl[4];
#pragma unroll
        for (int ks = 0; ks < 4; ++ks) {
          bh[ks] = *(const s16x8*)(cf + ((size_t)((nt * 4 + ks) * 2 + 0) * 64 + lane) * 8);
          bl[ks] = *(const s16x8*)(cf + ((size_t)((nt * 4 + ks) * 2 + 1) * 64 + lane) * 8);
        }
        fp32x16 acc0, acc1;
#pragma unroll
        for (int r = 0; r < 16; ++r) { acc0[r] = 0.f; acc1[r] = 0.f; }
        __builtin_amdgcn_s_setprio(1);   // T5 (A/B: -6us on rq)
#pragma unroll
        for (int ks = 0; ks < 4; ++ks) {
          acc0 = __builtin_amdgcn_mfma_f32_32x32x16_bf16(ah[0][ks], bh[ks], acc0, 0, 0, 0);
          acc1 = __builtin_amdgcn_mfma_f32_32x32x16_bf16(ah[1][ks], bh[ks], acc1, 0, 0, 0);
          acc0 = __builtin_amdgcn_mfma_f32_32x32x16_bf16(ah[0][ks], bl[ks], acc0, 0, 0, 0);
          acc1 = __builtin_amdgcn_mfma_f32_32x32x16_bf16(ah[1][ks], bl[ks], acc1, 0, 0, 0);
          acc0 = __builtin_amdgcn_mfma_f32_32x32x16_bf16(al[0][ks], bh[ks], acc0, 0, 0, 0);
          acc1 = __builtin_amdgcn_mfma_f32_32x32x16_bf16(al[1][ks], bh[ks], acc1, 0, 0, 0);
        }
        __builtin_amdgcn_s_setprio(0);
#pragma unroll
        for (int r = 0; r < 16; ++r) {
          float d0 = fmaf(-2.f, acc0[r], cnv);
          bool c0 = d0 < v1[0][r];
          v2[0][r] = c0 ? v1[0][r] : fminf(v2[0][r], d0);
          v1[0][r] = c0 ? d0 : v1[0][r];
          i1[0][r] = c0 ? kbase : i1[0][r];
          float d1 = fmaf(-2.f, acc1[r], cnv);
          bool c1 = d1 < v1[1][r];
          v2[1][r] = c1 ? v1[1][r] : fminf(v2[1][r], d1);
          v1[1][r] = c1 ? d1 : v1[1][r];
          i1[1][r] = c1 ? kbase : i1[1][r];
        }
      }
    }

    // ---- P3: per-row min across lanes + both chalf waves; candidates ----
#pragma unroll
    for (int m = 0; m < 2; ++m)
#pragma unroll
      for (int r = 0; r < 16; ++r) {
        float m1 = v1[m][r];
        m1 = fminf(m1, __shfl_xor(m1, 1));
        m1 = fminf(m1, __shfl_xor(m1, 2));
        m1 = fminf(m1, __shfl_xor(m1, 4));
        m1 = fminf(m1, __shfl_xor(m1, 8));
        m1 = fminf(m1, __shfl_xor(m1, 16));
        const int rowloc = rgrp * 64 + m * 32 + (r & 3) + 8 * (r >> 2) + 4 * half;
        if (lcol == 0) m1S[rowloc][chalf] = m1;
      }
    __syncthreads();
#pragma unroll
    for (int m = 0; m < 2; ++m)
#pragma unroll
      for (int r = 0; r < 16; ++r) {
        const int rowloc = rgrp * 64 + m * 32 + (r & 3) + 8 * (r >> 2) + 4 * half;
        float thr = fminf(m1S[rowloc][0], m1S[rowloc][1]) + DELTA;
        unsigned long long bc = __ballot(v1[m][r] <= thr);
        unsigned long long bf = __ballot(v2[m][r] <= thr);
        unsigned mc = (unsigned)(bc >> (half * 32));
        unsigned mf = (unsigned)(bf >> (half * 32));
        int pos = __popc(mc & ((1u << lcol) - 1u));
        if (v1[m][r] <= thr && pos < 4) candS[rowloc][chalf * 4 + pos] = i1[m][r];
        if (lcol == 0) {
          int c = __popc(mc);
          cntS[rowloc][chalf]  = (c < 4) ? c : 4;
          flagS[rowloc][chalf] = (mf != 0u) || (c > 4);
        }
      }
    __syncthreads();

    // ---- Phase A: exact np recompute for candidates (unflagged rows) ----
    if (tid < 128) {
      const int t = tid;
      if ((flagS[t][0] | flagS[t][1]) == 0) {
        const float* rp = resL + (size_t)(rb0 + t) * LAT;
        float rr[64];
#pragma unroll
        for (int j = 0; j < 16; ++j) {
          float4 x = *(const float4*)(rp + j * 4);
          rr[j * 4 + 0] = x.x; rr[j * 4 + 1] = x.y;
          rr[j * 4 + 2] = x.z; rr[j * 4 + 3] = x.w;
        }
        const float rn = rnS[t];
        float bd = FLT_MAX; int bk = 0x7fffffff;
        const int c0 = cntS[t][0], c1n = cntS[t][1];
        for (int c = 0; c < c0 + c1n; ++c) {
          int k = candS[t][(c < c0) ? c : (4 + c - c0)];
          const float* cp = cbL + (size_t)k * LAT;
          float dot = 0.f;
#pragma unroll
          for (int j = 0; j < 64; ++j) dot = fmaf(rr[j], cp[j], dot);
          float d = __fadd_rn(__fsub_rn(rn, __fmul_rn(2.f, dot)), cnL[k]);
          if (d < bd || (d == bd && k < bk)) { bd = d; bk = k; }
        }
        selS[t] = bk;
        out_codes[(size_t)layer * NB + rb0 + t] = (float)bk;
      }
    }
    __syncthreads();

    // ---- Phase B: flagged rows -> full exact scan (rare) ----
#pragma unroll 1
    for (int t2 = 0; t2 < 128; ++t2) {
      if ((flagS[t2][0] | flagS[t2][1]) == 0) continue;
      const float* rp = resL + (size_t)(rb0 + t2) * LAT;
      const float rn = rnS[t2];
      float bd = FLT_MAX; int bk = 0x7fffffff;
#pragma unroll 1
      for (int j = 0; j < 8; ++j) {
        int k = tid * 8 + j;
        const float* cp = cbL + (size_t)k * LAT;
        float dot = 0.f;
        for (int q = 0; q < 64; ++q) dot = fmaf(rp[q], cp[q], dot);
        float d = __fadd_rn(__fsub_rn(rn, __fmul_rn(2.f, dot)), cnL[k]);
        if (d < bd || (d == bd && k < bk)) { bd = d; bk = k; }
      }
      bestD[tid] = bd; bestK[tid] = bk;
      __syncthreads();
      if (tid == 0) {
        float gd = FLT_MAX; int gk = 0x7fffffff;
        for (int i = 0; i < 256; ++i) {
          float d = bestD[i]; int k = bestK[i];
          if (d < gd || (d == gd && k < gk)) { gd = d; gk = k; }
        }
        selS[t2] = gk;
        out_codes[(size_t)layer * NB + rb0 + t2] = (float)gk;
      }
      __syncthreads();
    }

    // ---- Phase Q: quantized = C[code] + quantized (np order) ----
    if (chalf == 0) {
#pragma unroll
      for (int m = 0; m < 2; ++m) {
        const int rowloc = rgrp * 64 + m * 32 + lcol;
        const size_t row = (size_t)(rb0 + rowloc);
        const int sel = selS[rowloc];
        const float* cp = cbL + (size_t)sel * LAT;
#pragma unroll
        for (int ks = 0; ks < 4; ++ks) {
          const int k0 = ks * 16 + half * 8;
          float4 c0 = *(const float4*)(cp + k0);
          float4 c1 = *(const float4*)(cp + k0 + 4);
          float* qp = out_quant + row * LAT + k0;
          if (layer == 0) {
            *(float4*)qp = c0; *(float4*)(qp + 4) = c1;
          } else {
            float4 q0 = *(const float4*)qp;
            float4 q1 = *(const float4*)(qp + 4);
            q0.x = __fadd_rn(c0.x, q0.x); q0.y = __fadd_rn(c0.y, q0.y);
            q0.z = __fadd_rn(c0.z, q0.z); q0.w = __fadd_rn(c0.w, q0.w);
            q1.x = __fadd_rn(c1.x, q1.x); q1.y = __fadd_rn(c1.y, q1.y);
            q1.z = __fadd_rn(c1.z, q1.z); q1.w = __fadd_rn(c1.w, q1.w);
            *(float4*)qp = q0; *(float4*)(qp + 4) = q1;
          }
        }
      }
    }
    __syncthreads();
  }
}

// ---------------------------------------------------------------------------
// dec1: h = relu(q @ dw1 + b1), split-bf16 MFMA (r10 variant, no setprio).
// ---------------------------------------------------------------------------
__global__ __launch_bounds__(256) void dec1_mfma(
    const float* __restrict__ q, const unsigned short* __restrict__ wf,
    const float* __restrict__ bias,
    unsigned short* __restrict__ h_hi, unsigned short* __restrict__ h_lo) {
  const int tid  = threadIdx.x;
  const int w    = tid >> 6;
  const int lane = tid & 63;
  const int half = lane >> 5;
  const int lcol = lane & 31;
  const int m0   = blockIdx.x * 128 + w * 32;
  const int n0   = blockIdx.y * 128;

  fp32x16 acc[4];
#pragma unroll
  for (int nt = 0; nt < 4; ++nt)
#pragma unroll
    for (int r = 0; r < 16; ++r) acc[nt][r] = 0.f;

  const size_t arow = (size_t)(m0 + lcol);
#pragma unroll
  for (int ks = 0; ks < 4; ++ks) {
    const float* ap = q + arow * LAT + ks * 16 + half * 8;
    float4 a0 = *(const float4*)ap;
    float4 a1 = *(const float4*)(ap + 4);
    float av[8] = {a0.x, a0.y, a0.z, a0.w, a1.x, a1.y, a1.z, a1.w};
    s16x8 ah, al;
#pragma unroll
    for (int i = 0; i < 8; ++i) {
      unsigned short hh = f2bf(av[i]);
      ah[i] = (short)hh;
      al[i] = (short)f2bf(__fsub_rn(av[i], bf2f(hh)));
    }
#pragma unroll
    for (int nt = 0; nt < 4; ++nt) {
      const int grp = ks * 8 + (blockIdx.y * 4 + nt);   // N/32 = 8
      const unsigned short* base = wf + (size_t)grp * 1024;
      s16x8 bh = *(const s16x8*)(base + lane * 8);
      s16x8 bl = *(const s16x8*)(base + 512 + lane * 8);
      acc[nt] = __builtin_amdgcn_mfma_f32_32x32x16_bf16(ah, bh, acc[nt], 0, 0, 0);
      acc[nt] = __builtin_amdgcn_mfma_f32_32x32x16_bf16(ah, bl, acc[nt], 0, 0, 0);
      acc[nt] = __builtin_amdgcn_mfma_f32_32x32x16_bf16(al, bh, acc[nt], 0, 0, 0);
    }
  }

#pragma unroll
  for (int nt = 0; nt < 4; ++nt) {
    const int col = n0 + nt * 32 + lcol;
    const float b = bias[col];
#pragma unroll
    for (int r = 0; r < 16; ++r) {
      const int rowo = (r & 3) + 8 * (r >> 2) + 4 * half;
      const size_t grow = (size_t)(m0 + rowo);
      float v = fmaxf(__fadd_rn(acc[nt][r], b), 0.f);
      unsigned short hh = f2bf(v);
      h_hi[grow * HID + col] = hh;
      h_lo[grow * HID + col] = f2bf(__fsub_rn(v, bf2f(hh)));
    }
  }
}

// ---------------------------------------------------------------------------
// dec2: x_recon = h @ dw2 + b2 (split-bf16 MFMA, r10 variant, no setprio).
// ---------------------------------------------------------------------------
__global__ __launch_bounds__(256) void dec2_mfma(
    const unsigned short* __restrict__ h_hi,
    const unsigned short* __restrict__ h_lo,
    const unsigned short* __restrict__ wf,
    const float* __restrict__ bias, float* __restrict__ C) {
  const int tid  = threadIdx.x;
  const int w    = tid >> 6;
  const int lane = tid & 63;
  const int half = lane >> 5;
  const int lcol = lane & 31;
  const int m0   = blockIdx.x * 128 + w * 32;
  const int n0   = blockIdx.y * 128;

  fp32x16 acc[4];
#pragma unroll
  for (int nt = 0; nt < 4; ++nt)
#pragma unroll
    for (int r = 0; r < 16; ++r) acc[nt][r] = 0.f;

  const size_t arow = (size_t)(m0 + lcol);
#pragma unroll 1
  for (int ks = 0; ks < 16; ++ks) {
    const size_t aoff = arow * HID + ks * 16 + half * 8;
    s16x8 ah = *(const s16x8*)(h_hi + aoff);
    s16x8 al = *(const s16x8*)(h_lo + aoff);
#pragma unroll
    for (int nt = 0; nt < 4; ++nt) {
      const int grp = ks * 16 + (blockIdx.y * 4 + nt);  // N/32 = 16
      const unsigned short* base = wf + (size_t)grp * 1024;
      s16x8 bh = *(const s16x8*)(base + lane * 8);
      s16x8 bl = *(const s16x8*)(base + 512 + lane * 8);
      acc[nt] = __builtin_amdgcn_mfma_f32_32x32x16_bf16(ah, bh, acc[nt], 0, 0, 0);
      acc[nt] = __builtin_amdgcn_mfma_f32_32x32x16_bf16(ah, bl, acc[nt], 0, 0, 0);
      acc[nt] = __builtin_amdgcn_mfma_f32_32x32x16_bf16(al, bh, acc[nt], 0, 0, 0);
    }
  }

#pragma unroll
  for (int nt = 0; nt < 4; ++nt) {
    const int col = n0 + nt * 32 + lcol;
    const float b = bias[col];
#pragma unroll
    for (int r = 0; r < 16; ++r) {
      const int rowo = (r & 3) + 8 * (r >> 2) + 4 * half;
      C[(size_t)(m0 + rowo) * IN_DIM + col] = __fadd_rn(acc[nt][r], b);
    }
  }
}

// ---------------------------------------------------------------------------
extern "C" void kernel_launch(void* const* d_in, const int* in_sizes, int n_in,
                              void* d_out, int out_size, void* d_ws, size_t ws_size,
                              hipStream_t stream) {
  (void)in_sizes; (void)n_in; (void)out_size;
  const float* x   = (const float*)d_in[0];
  const float* ew1 = (const float*)d_in[1];
  const float* eb1 = (const float*)d_in[2];
  const float* ew2 = (const float*)d_in[3];
  const float* eb2 = (const float*)d_in[4];
  const float* cbk = (const float*)d_in[5];
  const float* dw1 = (const float*)d_in[6];
  const float* db1 = (const float*)d_in[7];
  const float* dw2 = (const float*)d_in[8];
  const float* db2 = (const float*)d_in[9];

  float* out     = (float*)d_out;
  float* o_codes = out;                                   // 3*B
  float* o_xrec  = out + (size_t)NLAYERS * NB;            // B*512
  float* o_quant = o_xrec + (size_t)NB * IN_DIM;          // B*64
  float* o_res   = o_quant + (size_t)NB * LAT;            // 3*B*64

  char* ws = (char*)d_ws;
  float* h            = (float*)ws;                                  // 64 MB
  unsigned short* hhi = (unsigned short*)ws;                         // 32 MB
  unsigned short* hlo = (unsigned short*)(ws + (size_t)32 * 1024 * 1024);
  float* cn           = (float*)(ws + (size_t)64 * 1024 * 1024);     // 24 KB
  unsigned short* w1f = (unsigned short*)(ws + (size_t)64 * 1024 * 1024 + 32768);
  unsigned short* w2f = (unsigned short*)(ws + (size_t)64 * 1024 * 1024 + 32768 + 65536);
  const size_t ws_need = (size_t)64 * 1024 * 1024 + 32768 + 65536 + 524288;
  const bool fast_dec = ws_size >= ws_need;

  // codebook frag splits in the dead-until-dec2 tail of o_xrec (rq-only read)
  unsigned short* cbf = (unsigned short*)(o_xrec + (size_t)16 * 1024 * 1024);

  cnorm_f32<<<(NLAYERS * NK + 255) / 256, 256, 0, stream>>>(cbk, cn);
  split_cb<<<192, 256, 0, stream>>>(cbk, cbf);
  if (fast_dec) {
    split_w<<<((LAT / 16) * (HID / 32) * 64 + 255) / 256, 256, 0, stream>>>(dw1, w1f, LAT, HID);
    split_w<<<((HID / 16) * (IN_DIM / 32) * 64 + 255) / 256, 256, 0, stream>>>(dw2, w2f, HID, IN_DIM);
  }
  // encoder (bit-exact fp32; z -> codes chain must be exact)
  gemm128<true ><<<dim3(NB / 128, HID / 128), 256, 0, stream>>>(x, ew1, eb1, h,     NB, HID, IN_DIM);
  gemm_f32<false><<<dim3(NB / 128, LAT / 64),  256, 0, stream>>>(h, ew2, eb2, o_res, NB, LAT, HID);
  // residual quantization (r3 + setprio-in-P2; codes exact)
  rq_mfma<<<NB / 128, 256, 0, stream>>>(o_res, cbk, cbf, cn, o_codes, o_quant, o_res);
  // decoder (split-bf16 MFMA, no setprio)
  if (fast_dec) {
    dec1_mfma<<<dim3(NB / 128, 2), 256, 0, stream>>>(o_quant, w1f, db1, hhi, hlo);
    dec2_mfma<<<dim3(NB / 128, 4), 256, 0, stream>>>(hhi, hlo, w2f, db2, o_xrec);
  } else {
    gemm128<true ><<<dim3(NB / 128, HID / 128),    256, 0, stream>>>(o_quant, dw1, db1, h,      NB, HID,    LAT);
    gemm128<false><<<dim3(NB / 128, IN_DIM / 128), 256, 0, stream>>>(h,       dw2, db2, o_xrec, NB, IN_DIM, HID);
  }
}